// Round 7
// baseline (224.362 us; speedup 1.0000x reference)
//
#include <hip/hip_runtime.h>
#include <hip/hip_bf16.h>

typedef __attribute__((ext_vector_type(8))) short short8;
typedef __attribute__((ext_vector_type(4))) float f32x4;
typedef __attribute__((ext_vector_type(2))) unsigned uint2v;

#define NN 90
#define FD 32
#define LOG2E 1.4426950408889634f

__device__ inline unsigned short f2bf(float f) {
  return __builtin_bit_cast(unsigned short, __float2bfloat16(f));
}
__device__ inline float bf2f(unsigned short h) {
  unsigned u = ((unsigned)h) << 16;
  return __builtin_bit_cast(float, u);
}
// packed pair: low16 = bf(a), high16 = bf(b)  (fuses to v_cvt_pk_bf16_f32)
__device__ inline unsigned pk2(float a, float b) {
  return (unsigned)f2bf(a) | ((unsigned)f2bf(b) << 16);
}
__device__ inline f32x4 mfma16(short8 a, short8 b, f32x4 c) {
  return __builtin_amdgcn_mfma_f32_16x16x32_bf16(a, b, c, 0, 0, 0);
}
__device__ inline void frag_cvt(f32x4 a, f32x4 b, short8& hi, short8& lo) {
  float v[8] = {a[0], a[1], a[2], a[3], b[0], b[1], b[2], b[3]};
  #pragma unroll
  for (int i = 0; i < 8; ++i) {
    unsigned short h = f2bf(v[i]);
    hi[i] = (short)h;
    lo[i] = (short)f2bf(v[i] - bf2f(h));
  }
}

__global__ __launch_bounds__(256, 3) void CAI_35141422416140_kernel(
    const float* __restrict__ sc, const float* __restrict__ fc,
    const float* __restrict__ we, float* __restrict__ out, int nb)
{
  const int b   = blockIdx.x;
  const int tid = threadIdx.x;
  const int w   = tid >> 6;
  const int l   = tid & 63;
  const int lg  = l >> 4;
  const int lj  = l & 15;

  // LDS 50752 B -> 3 blocks/CU (12 waves)
  __shared__ __align__(16) char lds[50752];
  unsigned short* St  = (unsigned short*)(lds + 0);      // [32][104]
  unsigned short* Ft  = (unsigned short*)(lds + 6656);   // [32][104]
  unsigned short* Ghi = (unsigned short*)(lds + 13312);  // [96][40]
  unsigned short* Glo = (unsigned short*)(lds + 20992);  // [96][40]
  unsigned short* E1T = (unsigned short*)(lds + 13312);  // [90][104] overlays G after P3
  unsigned short* ERm = (unsigned short*)(lds + 32032);  // [90][104]

  const float* Sg = sc + (size_t)b * (NN * FD);
  const float* Fg = fc + (size_t)b * (NN * FD);

  // P1: coalesced scalar loads -> transposed bf16 St/Ft, packed b64 writes
  #pragma unroll
  for (int s = 0; s < 3; ++s) {
    int u  = s * 256 + tid;        // 0..767 = 32 d x 24 n-quads
    int d  = u & 31;
    int n0 = (u >> 5) * 4;         // 0..92
    float sv[4], fv[4];
    #pragma unroll
    for (int r = 0; r < 4; ++r) {
      bool ok = (n0 + r) < NN;
      sv[r] = ok ? Sg[(n0 + r) * FD + d] : 0.f;
      fv[r] = ok ? Fg[(n0 + r) * FD + d] : 0.f;
    }
    uint2v sp = { pk2(sv[0], sv[1]), pk2(sv[2], sv[3]) };
    uint2v fp = { pk2(fv[0], fv[1]), pk2(fv[2], fv[3]) };
    *(uint2v*)&St[d * 104 + n0] = sp;
    *(uint2v*)&Ft[d * 104 + n0] = fp;
  }

  // P0: W B-fragments (hi/lo), pre-scaled by log2e (exp -> exp2)
  short8 Wh[2], Wl[2];
  #pragma unroll
  for (int nt = 0; nt < 2; ++nt) {
    #pragma unroll
    for (int e = 0; e < 8; ++e) {
      float wv = we[(lg * 8 + e) * FD + nt * 16 + lj] * LOG2E;
      unsigned short h = f2bf(wv);
      Wh[nt][e] = (short)h;
      Wl[nt][e] = (short)f2bf(wv - bf2f(h));
    }
  }

  // P2: G = F*W (split precision), 6 row-tiles over 4 waves
  #pragma unroll
  for (int rep = 0; rep < 2; ++rep) {
    int mt = w + rep * 4;
    if (mt <= 5) {
      int row = mt * 16 + lj; if (row > NN - 1) row = NN - 1;
      f32x4 f0 = *(const f32x4*)(Fg + row * FD + lg * 8);
      f32x4 f1 = *(const f32x4*)(Fg + row * FD + lg * 8 + 4);
      short8 fh, fl;
      frag_cvt(f0, f1, fh, fl);
      #pragma unroll
      for (int nt = 0; nt < 2; ++nt) {
        f32x4 g = {0.f, 0.f, 0.f, 0.f};
        g = mfma16(fh, Wh[nt], g);
        g = mfma16(fh, Wl[nt], g);
        g = mfma16(fl, Wh[nt], g);
        #pragma unroll
        for (int q = 0; q < 4; ++q) {
          int grow = mt * 16 + lg * 4 + q;
          unsigned short gh = f2bf(g[q]);
          Ghi[grow * 40 + nt * 16 + lj] = gh;
          Glo[grow * 40 + nt * 16 + lj] = f2bf(g[q] - bf2f(gh));
        }
      }
    }
  }
  __syncthreads();

  // P3: quadrant tiling — wave w owns nt in [3*(w>>1), +3), mt in [3*(w&1), +3).
  // G fragments for the 3 mt tiles loaded ONCE into registers, reused over 3 nt.
  const int ntq = (w >> 1) * 3, mtq = (w & 1) * 3;
  short8 gh8[3], gl8[3];
  #pragma unroll
  for (int im = 0; im < 3; ++im) {
    gh8[im] = *(const short8*)&Ghi[((mtq + im) * 16 + lj) * 40 + lg * 8];
    gl8[im] = *(const short8*)&Glo[((mtq + im) * 16 + lj) * 40 + lg * 8];
  }
  f32x4 a_acc[9], t_acc[9];
  #pragma unroll
  for (int in = 0; in < 3; ++in) {
    int row = (ntq + in) * 16 + lj; if (row > NN - 1) row = NN - 1;
    f32x4 s0 = *(const f32x4*)(Sg + row * FD + lg * 8);
    f32x4 s1 = *(const f32x4*)(Sg + row * FD + lg * 8 + 4);
    short8 sh8, sl8;
    frag_cvt(s0, s1, sh8, sl8);
    #pragma unroll
    for (int im = 0; im < 3; ++im) {
      f32x4 a = {0.f, 0.f, 0.f, 0.f};
      a = mfma16(sh8, gh8[im], a);
      a = mfma16(sh8, gl8[im], a);
      a = mfma16(sl8, gh8[im], a);
      a_acc[in * 3 + im] = a;
      f32x4 t = {0.f, 0.f, 0.f, 0.f};
      t = mfma16(gh8[im], sh8, t);
      t = mfma16(gh8[im], sl8, t);
      t = mfma16(gl8[im], sh8, t);
      t_acc[in * 3 + im] = t;
    }
  }
  __syncthreads();  // all G reads done; E1T overlay safe

  // P4: exp2 + packed b64 writes of BOTH layouts
  const unsigned edge_lo = (lg < 3) ? 0xFFFFFFFFu : 0u;  // block-5 cols 4lg+{0,1} < 10
  const unsigned edge_hi = (lg < 2) ? 0xFFFFFFFFu : 0u;  // block-5 cols 4lg+{2,3} < 10
  #pragma unroll
  for (int i = 0; i < 9; ++i) {
    int nt = ntq + i / 3, mt = mtq + i % 3;
    f32x4 a = a_acc[i], t = t_acc[i];
    #pragma unroll
    for (int q = 0; q < 4; ++q) {
      a[q] = __builtin_amdgcn_exp2f(a[q]);
      t[q] = __builtin_amdgcn_exp2f(t[q]);
    }
    unsigned a0 = pk2(a[0], a[1]), a1 = pk2(a[2], a[3]);
    if (nt == 5) { a0 &= edge_lo; a1 &= edge_hi; }
    int rowm = mt * 16 + lj;
    if (rowm < NN) {
      uint2v pk = {a0, a1};
      *(uint2v*)&E1T[rowm * 104 + nt * 16 + lg * 4] = pk;
    }
    unsigned t0 = pk2(t[0], t[1]), t1 = pk2(t[2], t[3]);
    if (mt == 5) { t0 &= edge_lo; t1 &= edge_hi; }
    int rown = nt * 16 + lj;
    if (rown < NN) {
      uint2v pk = {t0, t1};
      *(uint2v*)&ERm[rown * 104 + mt * 16 + lg * 4] = pk;
    }
  }
  __syncthreads();

  const short ONE = (short)0x3F80;  // bf16 1.0
  const short8 ones = {ONE, ONE, ONE, ONE, ONE, ONE, ONE, ONE};
  const size_t ob1 = (size_t)b * (NN * FD);
  const size_t ob2 = (size_t)nb * (NN * FD) + ob1;

  // P5a: cosc[m][d] = sum_n E1T[m][n]*S[n][d] / csum[m]
  {
    f32x4 inv; int curmt = -1;
    #pragma unroll
    for (int i = 0; i < 3; ++i) {
      int t5 = 3 * w + i;
      int mt = t5 >> 1, dt = t5 & 1;
      bool newmt = (mt != curmt);
      int arow = mt * 16 + lj; if (arow > NN - 1) arow = NN - 1;
      f32x4 o = {0.f, 0.f, 0.f, 0.f};
      f32x4 s4 = {0.f, 0.f, 0.f, 0.f};
      #pragma unroll
      for (int ks = 0; ks < 3; ++ks) {
        short8 af = *(const short8*)&E1T[arow * 104 + ks * 32 + lg * 8];
        short8 bf = *(const short8*)&St [(dt * 16 + lj) * 104 + ks * 32 + lg * 8];
        o = mfma16(af, bf, o);
        if (newmt) s4 = mfma16(af, ones, s4);
      }
      if (newmt) {
        #pragma unroll
        for (int q = 0; q < 4; ++q) inv[q] = __builtin_amdgcn_rcpf(s4[q]);
        curmt = mt;
      }
      #pragma unroll
      for (int q = 0; q < 4; ++q) {
        int m = mt * 16 + lg * 4 + q;
        if (m < NN) out[ob1 + m * FD + dt * 16 + lj] = o[q] * inv[q];
      }
    }
  }

  // P5b: cofc[n][d] = sum_m ERm[n][m]*F[m][d] / rsum[n]   (no barrier needed)
  {
    f32x4 inv; int curnt = -1;
    #pragma unroll
    for (int i = 0; i < 3; ++i) {
      int t5 = 3 * w + i;
      int ntt = t5 >> 1, dt = t5 & 1;
      bool newnt = (ntt != curnt);
      int arow = ntt * 16 + lj; if (arow > NN - 1) arow = NN - 1;
      f32x4 o = {0.f, 0.f, 0.f, 0.f};
      f32x4 s4 = {0.f, 0.f, 0.f, 0.f};
      #pragma unroll
      for (int ks = 0; ks < 3; ++ks) {
        short8 af = *(const short8*)&ERm[arow * 104 + ks * 32 + lg * 8];
        short8 bf = *(const short8*)&Ft [(dt * 16 + lj) * 104 + ks * 32 + lg * 8];
        o = mfma16(af, bf, o);
        if (newnt) s4 = mfma16(af, ones, s4);
      }
      if (newnt) {
        #pragma unroll
        for (int q = 0; q < 4; ++q) inv[q] = __builtin_amdgcn_rcpf(s4[q]);
        curnt = ntt;
      }
      #pragma unroll
      for (int q = 0; q < 4; ++q) {
        int n = ntt * 16 + lg * 4 + q;
        if (n < NN) out[ob2 + n * FD + dt * 16 + lj] = o[q] * inv[q];
      }
    }
  }
}

extern "C" void kernel_launch(void* const* d_in, const int* in_sizes, int n_in,
                              void* d_out, int out_size, void* d_ws, size_t ws_size,
                              hipStream_t stream) {
  const float* sc = (const float*)d_in[0];
  const float* fc = (const float*)d_in[1];
  const float* we = (const float*)d_in[2];
  float* out = (float*)d_out;
  int nb = in_sizes[0] / (NN * FD);  // 8192
  CAI_35141422416140_kernel<<<dim3(nb), dim3(256), 0, stream>>>(sc, fc, we, out, nb);
}